// Round 2
// baseline (118.579 us; speedup 1.0000x reference)
//
#include <hip/hip_runtime.h>

// Problem:
//   pos:    [1, 64, 1024]   float32
//   events: [2, 64, 131072] float32
//   out:    [2, 64, 131072] float32
// Semantics: out[b,e,t] = events[b,e,t-d_e] for t>=d_e else 0,
// where d_e = argmax(pos[0,e,:]) * (131072/1024).
//
// Single fused kernel: every block recomputes its event's argmax locally
// (pos row = 4 KB, L2-resident), then does its slice of the shifted copy.
// No d_ws, no cross-kernel dependency — deterministic given d_in only.
// (Round-1 failure: two-kernel version handed shift through d_ws; timing
// phase consumed poisoned d_ws — fused version is immune by construction.)

#define N_EVENTS 64
#define START_SIZE 1024
#define N_SAMPLES 131072
#define BATCH 2
#define FACTOR (N_SAMPLES / START_SIZE)      // 128
#define ROW_LEN4 (N_SAMPLES / 4)             // 32768 float4 per row
#define BLOCKS_PER_ROW 16
#define CHUNK4 (ROW_LEN4 / BLOCKS_PER_ROW)   // 2048 float4 per block
#define ITERS (CHUNK4 / 256)                 // 8 float4 per thread

__global__ __launch_bounds__(256) void dirac_fused_kernel(
        const float4* __restrict__ pos4,     // [64, 256] float4
        const float4* __restrict__ ev,       // [128, 32768] float4
        float4* __restrict__ out) {
    const int row   = blockIdx.x >> 4;       // 0..127  (b*64+e)
    const int chunk = blockIdx.x & (BLOCKS_PER_ROW - 1);
    const int e     = row & (N_EVENTS - 1);
    const int tid   = threadIdx.x;           // 0..255

    // ---- local argmax over pos[e][0..1023] (first-occurrence ties) ----
    float4 p = pos4[e * 256 + tid];
    float v = p.x; int bi = 4 * tid;
    if (p.y > v) { v = p.y; bi = 4 * tid + 1; }
    if (p.z > v) { v = p.z; bi = 4 * tid + 2; }
    if (p.w > v) { v = p.w; bi = 4 * tid + 3; }

    #pragma unroll
    for (int off = 32; off >= 1; off >>= 1) {
        float ov = __shfl_down(v, off, 64);
        int   oi = __shfl_down(bi, off, 64);
        if (ov > v || (ov == v && oi < bi)) { v = ov; bi = oi; }
    }

    __shared__ float sv[4];
    __shared__ int   si[4];
    if ((tid & 63) == 0) { sv[tid >> 6] = v; si[tid >> 6] = bi; }
    __syncthreads();

    float bv = sv[0]; int b = si[0];
    #pragma unroll
    for (int w = 1; w < 4; ++w) {
        if (sv[w] > bv || (sv[w] == bv && si[w] < b)) { bv = sv[w]; b = si[w]; }
    }
    const int d4 = b * (FACTOR / 4);         // float4-granular shift (mult of 32)

    // ---- shifted copy of this block's 2048-float4 contiguous chunk ----
    const int rowbase = row * ROW_LEN4;
    int t4 = chunk * CHUNK4 + tid;
    #pragma unroll
    for (int it = 0; it < ITERS; ++it, t4 += 256) {
        float4 val = make_float4(0.f, 0.f, 0.f, 0.f);
        if (t4 >= d4) {
            val = ev[rowbase + (t4 - d4)];
        }
        out[rowbase + t4] = val;
    }
}

extern "C" void kernel_launch(void* const* d_in, const int* in_sizes, int n_in,
                              void* d_out, int out_size, void* d_ws, size_t ws_size,
                              hipStream_t stream) {
    const float4* pos4 = (const float4*)d_in[0];
    const float4* ev   = (const float4*)d_in[1];
    float4* out = (float4*)d_out;

    const int nblocks = BATCH * N_EVENTS * BLOCKS_PER_ROW;   // 2048
    dirac_fused_kernel<<<nblocks, 256, 0, stream>>>(pos4, ev, out);
}